// Round 19
// baseline (2835.591 us; speedup 1.0000x reference)
//
#include <hip/hip_runtime.h>

// LSTM 2-layer — DUAL-ENGINE v4 (margin probe): 512 blocks x 512 thr.
// Blocks [0,256) = L0 of row b; [256,512) = L1 of row b-256.
// Unified-file re-read of R13..R18: VGPR_Count INCLUDES accumulators
// (gfx950 unified file); every co-residency failure was an EXACT fit
// (R17: 4x128=512; R15: 2x256=512; R18: LDS 159,744/163,840 + spill at
// cap96 < live 109). m97 precedent: 3x164=492<512 co-resides.
// v4 gives strict margins on BOTH resources:
//   VGPR: amdgpu_num_vgpr(112) -> 4 waves/SIMD x 112 = 448 << 512;
//         live ~104 (48 wght + 16 acc + ~40 temps) -> no spill.
//   LDS:  TC=8 -> 56,352 B/block (xp f32 16K + slice3 W 32K + bufs) ->
//         2x = 112.7K << 160K (granule-proof).
// Weights: slices 0-2 in regs (12 frags, KEEP-pinned), slice 3 in LDS
// (R18 mechanism, numerically verified identical). All arithmetic =
// R13/R17/R18 -> absmax must stay 1.2207e-4 exactly.
// Handoff: full-size h0g in d_ws (deadlock-free) + per-row counters,
// agent-scope release/acquire. d_ws requirement: 134,677,504 B.

typedef __attribute__((ext_vector_type(4))) float f32x4;
typedef _Float16 f16x8 __attribute__((ext_vector_type(8)));
typedef short s16x8 __attribute__((ext_vector_type(8)));

#define NB    256
#define TSEQ  1024
#define II    64
#define HH    128
#define G4    512
#define TC    8
#define NCH   (TSEQ/TC)       // 128
#define SCL   0.0009765625f   // 2^-10
#define SCLI  1024.f          // 2^10

// ws frag regions (16B units), R13 layout: idx = region + ((w*4+t4)*NKS+s)*64 + lane.
#define F_WHH0  0
#define F_WHH1  8192
#define F_WIH1  16384
#define F_WIH0  24576
#define F_TOTAL 28672

#define H0G_OFF   458752ULL
#define H0G_WORDS (256ULL*1024ULL*128ULL)
#define FLAG_OFF  (H0G_OFF + H0G_WORDS*4ULL)
#define WS_NEEDED (FLAG_OFF + 1024ULL)   // 134,677,504

// smem layout (per block): xp 16,384 | WL 32,768 | engine bufs
#define L_XP   0
#define L_WL   16384
#define L_ENG  49152

#define KEEP4I(v) asm volatile("" : "+v"((v).x), "+v"((v).y), "+v"((v).z), "+v"((v).w))

__device__ __forceinline__ float tanh_f(float x){
    float ax = fabsf(x);
    float e  = __expf(2.f*ax);
    float t  = 1.f - 2.f*__builtin_amdgcn_rcpf(e + 1.f);
    return copysignf(t, x);
}
__device__ __forceinline__ f32x4 mfma16(int4 a, f16x8 b, f32x4 c){
    return __builtin_amdgcn_mfma_f32_16x16x32_f16(
        __builtin_bit_cast(f16x8, a), b, c, 0, 0, 0);
}
__device__ __forceinline__ f16x8 ldb(const _Float16* p){
    return __builtin_bit_cast(f16x8, *(const int4*)p);
}
__device__ __forceinline__ void unpack8(int4 v0, int4 v1, f16x8& bh, f16x8& bl){
    s16x8 hb, lb;
    hb[0]=(short)v0.x; lb[0]=(short)(((unsigned)v0.x)>>16);
    hb[1]=(short)v0.y; lb[1]=(short)(((unsigned)v0.y)>>16);
    hb[2]=(short)v0.z; lb[2]=(short)(((unsigned)v0.z)>>16);
    hb[3]=(short)v0.w; lb[3]=(short)(((unsigned)v0.w)>>16);
    hb[4]=(short)v1.x; lb[4]=(short)(((unsigned)v1.x)>>16);
    hb[5]=(short)v1.y; lb[5]=(short)(((unsigned)v1.y)>>16);
    hb[6]=(short)v1.z; lb[6]=(short)(((unsigned)v1.z)>>16);
    hb[7]=(short)v1.w; lb[7]=(short)(((unsigned)v1.w)>>16);
    bh = __builtin_bit_cast(f16x8, hb);
    bl = __builtin_bit_cast(f16x8, lb);
}

// ---------------- pack kernel (R13 verbatim): fp32 -> fp16 A-fragments -----
__global__ void pack_w(const float* __restrict__ Wih0, const float* __restrict__ Whh0,
                       const float* __restrict__ Wih1, const float* __restrict__ Whh1,
                       int4* __restrict__ ws)
{
    int fid = blockIdx.x * 256 + threadIdx.x;
    if (fid >= F_TOTAL) return;
    const float* src; int nks; int rb;
    if (fid < F_WHH1)      { src = Whh0; nks = 4; rb = fid; }
    else if (fid < F_WIH1) { src = Whh1; nks = 4; rb = fid - F_WHH1; }
    else if (fid < F_WIH0) { src = Wih1; nks = 4; rb = fid - F_WIH1; }
    else                   { src = Wih0; nks = 2; rb = fid - F_WIH0; }
    int lane = rb & 63;
    int rem  = rb >> 6;
    int s    = rem % nks;
    int t    = (rem / nks) & 3;
    int w    = rem / (nks * 4);
    int row  = t * 128 + w * 16 + (lane & 15);
    int K    = nks * 32;
    int k0   = s * 32 + (lane >> 4) * 8;
    const float* p = src + (size_t)row * K + k0;
    unsigned short us[8];
    #pragma unroll
    for (int j = 0; j < 8; ++j)
        us[j] = __builtin_bit_cast(unsigned short, (_Float16)p[j]);
    int4 o;
    o.x = (int)((unsigned)us[0] | ((unsigned)us[1] << 16));
    o.y = (int)((unsigned)us[2] | ((unsigned)us[3] << 16));
    o.z = (int)((unsigned)us[4] | ((unsigned)us[5] << 16));
    o.w = (int)((unsigned)us[6] | ((unsigned)us[7] << 16));
    ws[fid] = o;
}

// ---------------- shared serial-step body (R13 math; slice3 from LDS) ------
struct LaneCtx {
    int gsel, usel, u, xpr, base;
    bool writer, is_g, odd;
    int lk;
};

template<bool PING>
__device__ __forceinline__ void serial_steps(
    const LaneCtx& L, const int4 (&Ahi)[4][3], const int4* wl, int lane,
    float (*xp)[G4],
    _Float16* hh_rd_base, _Float16* hl_rd_base, int rd_stride,
    _Float16* hh_wr_base, _Float16* hl_wr_base, int wr_stride,
    float* h1f, float& c)
{
    #pragma unroll 1
    for (int t = 0; t < TC; ++t){
        int rs = PING ? (t & 1) : t;
        int wsl = PING ? ((t+1) & 1) : (t+1);
        const _Float16* bp = L.odd ? (hl_rd_base + rs*rd_stride)
                                   : (hh_rd_base + rs*rd_stride);
        float xpv = xp[t][L.xpr];
        f32x4 acc[4];
        #pragma unroll
        for (int t4 = 0; t4 < 4; ++t4) acc[t4] = (f32x4){0.f,0.f,0.f,0.f};
        #pragma unroll
        for (int s = 0; s < 3; ++s){
            f16x8 bv = ldb(&bp[s*32 + L.lk*8]);
            #pragma unroll
            for (int t4 = 0; t4 < 4; ++t4) acc[t4] = mfma16(Ahi[t4][s], bv, acc[t4]);
        }
        {   // slice s=3: weights from LDS
            f16x8 bv = ldb(&bp[96 + L.lk*8]);
            int4 a0 = wl[0*64 + lane];
            int4 a1 = wl[1*64 + lane];
            int4 a2 = wl[2*64 + lane];
            int4 a3 = wl[3*64 + lane];
            acc[0] = mfma16(a0, bv, acc[0]);
            acc[1] = mfma16(a1, bv, acc[1]);
            acc[2] = mfma16(a2, bv, acc[2]);
            acc[3] = mfma16(a3, bv, acc[3]);
        }
        f32x4 ps;
        {
            f32x4 p01 = (L.gsel & 1) ? acc[1] : acc[0];
            f32x4 p23 = (L.gsel & 1) ? acc[3] : acc[2];
            ps = (L.gsel & 2) ? p23 : p01;
        }
        float own, oth;
        {
            float a01 = (L.usel & 1) ? ps[1] : ps[0];
            float a23 = (L.usel & 1) ? ps[3] : ps[2];
            own = (L.usel & 2) ? a23 : a01;
            float b01 = (L.usel & 1) ? ps[0] : ps[1];
            float b23 = (L.usel & 1) ? ps[2] : ps[3];
            oth = (L.usel & 2) ? b23 : b01;
        }
        float recv = __shfl_xor(oth, 1);
        float pre  = (L.odd ? (recv + SCL*own) : (own + SCL*recv)) + xpv;
        float z    = tanh_f(L.is_g ? pre : 0.5f*pre);
        float y    = L.is_g ? z : 0.5f*z + 0.5f;
        float gi = __shfl(y, L.base);
        float gf = __shfl(y, L.base | 4);
        float gg = __shfl(y, L.base | 8);
        float go = __shfl(y, L.base | 12);
        c = gf*c + gi*gg;
        float h = go * tanh_f(c);
        _Float16 hf = (_Float16)h;
        _Float16 hl = (_Float16)((h - (float)hf) * SCLI);
        if (L.writer){
            (hh_wr_base + wsl*wr_stride)[L.u] = hf;
            (hl_wr_base + wsl*wr_stride)[L.u] = hl;
            if (h1f) h1f[L.u] = h;
        }
        __syncthreads();
    }
}

// ---------------- dual-engine persistent kernel ----------------------------
__global__ __launch_bounds__(512, 2) __attribute__((amdgpu_num_vgpr(112)))
void lstm_dual(const float* __restrict__ x,
               const float* __restrict__ bih0, const float* __restrict__ bhh0,
               const float* __restrict__ bih1, const float* __restrict__ bhh1,
               const float* __restrict__ Wlin, const float* __restrict__ blin,
               const int4* __restrict__ ws,
               unsigned* __restrict__ h0g,
               int* __restrict__ prod,
               float* __restrict__ out)
{
    const int tid  = threadIdx.x;
    const int lane = tid & 63;
    const int w    = tid >> 6;          // wave 0..7
    const int lm   = lane & 15;
    const int lk   = lane >> 4;

    LaneCtx L;
    L.gsel = lm >> 2;  L.usel = lm & 3;  L.lk = lk;
    L.u    = w*16 + lk*4 + L.usel;
    L.xpr  = L.gsel*128 + w*16 + lk*4 + L.usel;
    L.base = lane & 0x33;
    L.writer = (L.gsel == 0);
    L.is_g   = (L.gsel == 2);
    L.odd    = (lane & 1);

    __shared__ __align__(16) char smem[56352];
    float (*xp)[G4] = (float(*)[G4])(smem + L_XP);
    int4*  WL       = (int4*)(smem + L_WL);
    const int4* wl  = WL + (w*4)*64;    // this wave's 4 slice-3 frags

    if (blockIdx.x < NB) {
        // =================== LAYER-0 ENGINE ===================
        const int row = blockIdx.x;
        _Float16 (*h0_hi)[136] = (_Float16(*)[136])(smem + L_ENG);          // 2,448
        _Float16 (*h0_lo)[136] = (_Float16(*)[136])(smem + L_ENG + 2448);   // 2,448
        _Float16 (*xc_hi)[72]  = (_Float16(*)[72]) (smem + L_ENG + 4896);   // 1,152
        _Float16 (*xc_lo)[72]  = (_Float16(*)[72]) (smem + L_ENG + 6048);   // 1,152

        if (tid < HH){ h0_hi[0][tid] = (_Float16)0.f; h0_lo[0][tid] = (_Float16)0.f; }
        #pragma unroll
        for (int t4 = 0; t4 < 4; ++t4)   // stage slice-3 weights once
            WL[(w*4 + t4)*64 + lane] = ws[F_WHH0 + (((w*4 + t4)*4 + 3) << 6) + lane];
        float c0 = 0.f;
        const float* xb = x + (size_t)row * TSEQ * II;
        __syncthreads();

        #pragma unroll 1
        for (int ch = 0; ch < NCH; ++ch){
            // ---- stage x chunk (512 floats, 1/thread); carry h0 ----
            {
                float v = xb[(size_t)ch*TC*II + tid];
                _Float16 a = (_Float16)v;
                xc_hi[tid>>6][tid&63] = a;
                xc_lo[tid>>6][tid&63] = (_Float16)((v - (float)a)*SCLI);
            }
            if (ch > 0 && tid < HH){
                h0_hi[0][tid] = h0_hi[TC][tid];
                h0_lo[0][tid] = h0_lo[TC][tid];
            }
            __syncthreads();

            // ---- proj xp0 (K=64, cols 0..7 used) ----
            {
                f32x4 acc[4], accL[4];
                #pragma unroll
                for (int t4 = 0; t4 < 4; ++t4){
                    acc[t4]  = (f32x4){0.f,0.f,0.f,0.f};
                    accL[t4] = (f32x4){0.f,0.f,0.f,0.f};
                }
                int xr = lm & 7;    // cols 8..15 duplicate (discarded)
                #pragma unroll
                for (int s = 0; s < 2; ++s){
                    f16x8 bh = ldb(&xc_hi[xr][s*32 + lk*8]);
                    f16x8 bl = ldb(&xc_lo[xr][s*32 + lk*8]);
                    int4 ah[4];
                    #pragma unroll
                    for (int t4 = 0; t4 < 4; ++t4)
                        ah[t4] = ws[F_WIH0 + (((w*4 + t4)*2 + s) << 6) + lane];
                    #pragma unroll
                    for (int t4 = 0; t4 < 4; ++t4) acc[t4]  = mfma16(ah[t4], bh, acc[t4]);
                    #pragma unroll
                    for (int t4 = 0; t4 < 4; ++t4) accL[t4] = mfma16(ah[t4], bl, accL[t4]);
                }
                if (lm < 8){
                    #pragma unroll
                    for (int t4 = 0; t4 < 4; ++t4){
                        int rowb = t4*128 + w*16 + lk*4;
                        f32x4 bs = *(const f32x4*)(bih0+rowb) + *(const f32x4*)(bhh0+rowb);
                        *(f32x4*)&xp[lm][rowb] = acc[t4] + accL[t4]*SCL + bs;
                    }
                }
            }
            __syncthreads();

            // ---- serial 8 steps (slices 0-2 arch, slice 3 LDS) ----
            int4 Ahi[4][3];
            #pragma unroll
            for (int t4 = 0; t4 < 4; ++t4)
                #pragma unroll
                for (int s = 0; s < 3; ++s)
                    Ahi[t4][s] = ws[F_WHH0 + (((w*4 + t4)*4 + s) << 6) + lane];
            #pragma unroll
            for (int t4 = 0; t4 < 4; ++t4)
                #pragma unroll
                for (int s = 0; s < 3; ++s) KEEP4I(Ahi[t4][s]);

            serial_steps<false>(L, Ahi, wl, lane, xp,
                                &h0_hi[0][0], &h0_lo[0][0], 136,
                                &h0_hi[0][0], &h0_lo[0][0], 136,
                                nullptr, c0);

            // ---- publish chunk (1,024 u32; 2/thread) ----
            {
                size_t gbase = ((size_t)row*TSEQ + (size_t)ch*TC)*HH;
                #pragma unroll
                for (int k = 0; k < 2; ++k){
                    int idx = tid + 512*k;
                    int t = idx >> 7, u = idx & 127;
                    unsigned ph = (unsigned)__builtin_bit_cast(unsigned short, h0_hi[t+1][u]);
                    unsigned pl = (unsigned)__builtin_bit_cast(unsigned short, h0_lo[t+1][u]);
                    h0g[gbase + idx] = ph | (pl << 16);
                }
            }
            __syncthreads();
            if (tid == 0)
                __hip_atomic_store(&prod[row], ch+1, __ATOMIC_RELEASE,
                                   __HIP_MEMORY_SCOPE_AGENT);
        }
    } else {
        // =================== LAYER-1 ENGINE ===================
        const int row = blockIdx.x - NB;
        _Float16 (*h1_hi)[HH] = (_Float16(*)[HH])(smem + L_ENG);        // 512
        _Float16 (*h1_lo)[HH] = (_Float16(*)[HH])(smem + L_ENG + 512);  // 512
        float*    h1f         = (float*)(smem + L_ENG + 1024);          // 512

        if (tid < HH){ h1_hi[0][tid] = (_Float16)0.f; h1_lo[0][tid] = (_Float16)0.f;
                       h1f[tid] = 0.f; }
        #pragma unroll
        for (int t4 = 0; t4 < 4; ++t4)   // stage slice-3 weights once
            WL[(w*4 + t4)*64 + lane] = ws[F_WHH1 + (((w*4 + t4)*4 + 3) << 6) + lane];
        float c1 = 0.f;
        __syncthreads();

        #pragma unroll 1
        for (int ch = 0; ch < NCH; ++ch){
            // ---- wait for h0 chunk ----
            {
                int v = __hip_atomic_load(&prod[row], __ATOMIC_RELAXED,
                                          __HIP_MEMORY_SCOPE_AGENT);
                while (v < ch+1){
                    __builtin_amdgcn_s_sleep(8);
                    v = __hip_atomic_load(&prod[row], __ATOMIC_RELAXED,
                                          __HIP_MEMORY_SCOPE_AGENT);
                }
                (void)__hip_atomic_load(&prod[row], __ATOMIC_ACQUIRE,
                                        __HIP_MEMORY_SCOPE_AGENT);
            }
            // ---- proj xp1 from global h0 chunk (K=128, cols 0..7 used) ----
            {
                f32x4 acc[4], accL[4];
                #pragma unroll
                for (int t4 = 0; t4 < 4; ++t4){
                    acc[t4]  = (f32x4){0.f,0.f,0.f,0.f};
                    accL[t4] = (f32x4){0.f,0.f,0.f,0.f};
                }
                size_t gbase = ((size_t)row*TSEQ + (size_t)ch*TC + (lm & 7))*HH;
                #pragma unroll
                for (int s = 0; s < 4; ++s){
                    const int4* gp = (const int4*)(h0g + gbase + s*32 + lk*8);
                    int4 v0 = gp[0], v1 = gp[1];
                    f16x8 bh, bl;
                    unpack8(v0, v1, bh, bl);
                    int4 ah[4];
                    #pragma unroll
                    for (int t4 = 0; t4 < 4; ++t4)
                        ah[t4] = ws[F_WIH1 + (((w*4 + t4)*4 + s) << 6) + lane];
                    #pragma unroll
                    for (int t4 = 0; t4 < 4; ++t4) acc[t4]  = mfma16(ah[t4], bh, acc[t4]);
                    #pragma unroll
                    for (int t4 = 0; t4 < 4; ++t4) accL[t4] = mfma16(ah[t4], bl, accL[t4]);
                }
                if (lm < 8){
                    #pragma unroll
                    for (int t4 = 0; t4 < 4; ++t4){
                        int rowb = t4*128 + w*16 + lk*4;
                        f32x4 bs = *(const f32x4*)(bih1+rowb) + *(const f32x4*)(bhh1+rowb);
                        *(f32x4*)&xp[lm][rowb] = acc[t4] + accL[t4]*SCL + bs;
                    }
                }
            }
            __syncthreads();

            // ---- serial 8 steps (ping-pong h1) ----
            int4 Ahi[4][3];
            #pragma unroll
            for (int t4 = 0; t4 < 4; ++t4)
                #pragma unroll
                for (int s = 0; s < 3; ++s)
                    Ahi[t4][s] = ws[F_WHH1 + (((w*4 + t4)*4 + s) << 6) + lane];
            #pragma unroll
            for (int t4 = 0; t4 < 4; ++t4)
                #pragma unroll
                for (int s = 0; s < 3; ++s) KEEP4I(Ahi[t4][s]);

            serial_steps<true>(L, Ahi, wl, lane, xp,
                               &h1_hi[0][0], &h1_lo[0][0], HH,
                               &h1_hi[0][0], &h1_lo[0][0], HH,
                               h1f, c1);
        }

        // ---- final linear ----
        if (tid < 64){
            float s = h1f[tid]*Wlin[tid] + h1f[tid+64]*Wlin[tid+64];
            #pragma unroll
            for (int off = 32; off; off >>= 1) s += __shfl_down(s, off);
            if (tid == 0) out[row] = s + blin[0];
        }
    }
}

extern "C" void kernel_launch(void* const* d_in, const int* in_sizes, int n_in,
                              void* d_out, int out_size, void* d_ws, size_t ws_size,
                              hipStream_t stream)
{
    const float* x    = (const float*)d_in[0];
    const float* Wih0 = (const float*)d_in[1];
    const float* Whh0 = (const float*)d_in[2];
    const float* bih0 = (const float*)d_in[3];
    const float* bhh0 = (const float*)d_in[4];
    const float* Wih1 = (const float*)d_in[5];
    const float* Whh1 = (const float*)d_in[6];
    const float* bih1 = (const float*)d_in[7];
    const float* bhh1 = (const float*)d_in[8];
    const float* Wlin = (const float*)d_in[9];
    const float* blin = (const float*)d_in[10];

    if (ws_size < WS_NEEDED) return;   // loud deterministic failure if ws too small

    char* wsb = (char*)d_ws;
    int4*     ws   = (int4*)wsb;
    unsigned* h0g  = (unsigned*)(wsb + H0G_OFF);
    int*      prod = (int*)(wsb + FLAG_OFF);

    (void)hipMemsetAsync(prod, 0, 1024, stream);
    hipLaunchKernelGGL(pack_w, dim3(F_TOTAL/256), dim3(256), 0, stream,
                       Wih0, Whh0, Wih1, Whh1, ws);
    hipLaunchKernelGGL(lstm_dual, dim3(2*NB), dim3(512), 0, stream,
                       x, bih0, bhh0, bih1, bhh1, Wlin, blin,
                       ws, h0g, prod, (float*)d_out);
}

// Round 20
// 1958.413 us; speedup vs baseline: 1.4479x; 1.4479x over previous
//
#include <hip/hip_runtime.h>

// LSTM 2-layer — FUSED DUAL-ENGINE: 256 blocks x 1024 thr (16 waves).
// Waves 0-7 = layer0 engine, waves 8-15 = layer1 engine (lag = 1 chunk,
// TC=16). ONE shared barrier per pair-step: the two engines' chains hide
// each other on the 4-waves/SIMD schedule. Handoff via LDS (same block) —
// no global buffer, no flags (R15/R17/R19's separate-block scheme never
// co-resided: scheduler policy, 3x proven).
// VGPR: amdgpu_num_vgpr(128) RAISES the 1024-thr grant from its 64 default
// (R18 proved the attribute is honored; m69: 16 waves/CU at 128 VGPR is a
// legal HW point). Live set ~110 = R13's (16 weight frags KEEP-pinned,
// reloaded per chunk so proj temps don't collide). waves_per_eu(4,4) +
// flat_work_group_size pin the occupancy target.
// All arithmetic = R13 verbatim (N-packed fp16 hi/lo cols, gate-major
// tiles, shfl_xor combine, wave-local c-update) -> absmax must stay
// 1.2207e-4 exactly. d_ws: 458,752 B (packed weights only).

typedef __attribute__((ext_vector_type(4))) float f32x4;
typedef _Float16 f16x8 __attribute__((ext_vector_type(8)));

#define NB    256
#define TSEQ  1024
#define II    64
#define HH    128
#define G4    512
#define TC    16
#define NCH   (TSEQ/TC)       // 64
#define SCL   0.0009765625f   // 2^-10
#define SCLI  1024.f          // 2^10

// ws frag regions (16B units), R13 layout: idx = region + ((w*4+t4)*NKS+s)*64 + lane.
#define F_WHH0  0
#define F_WHH1  8192
#define F_WIH1  16384
#define F_WIH0  24576
#define F_TOTAL 28672         // *16B = 458,752 B

#define KEEP4I(v) asm volatile("" : "+v"((v).x), "+v"((v).y), "+v"((v).z), "+v"((v).w))

__device__ __forceinline__ float tanh_f(float x){
    float ax = fabsf(x);
    float e  = __expf(2.f*ax);
    float t  = 1.f - 2.f*__builtin_amdgcn_rcpf(e + 1.f);
    return copysignf(t, x);
}
__device__ __forceinline__ f32x4 mfma16(int4 a, f16x8 b, f32x4 c){
    return __builtin_amdgcn_mfma_f32_16x16x32_f16(
        __builtin_bit_cast(f16x8, a), b, c, 0, 0, 0);
}
__device__ __forceinline__ f16x8 ldb(const _Float16* p){
    return __builtin_bit_cast(f16x8, *(const int4*)p);
}

// ---------------- pack kernel (R13 verbatim): fp32 -> fp16 A-fragments -----
// row = t4*128 + w*16 + (lane&15); k = s*32 + (lane>>4)*8 + j.
__global__ void pack_w(const float* __restrict__ Wih0, const float* __restrict__ Whh0,
                       const float* __restrict__ Wih1, const float* __restrict__ Whh1,
                       int4* __restrict__ ws)
{
    int fid = blockIdx.x * 256 + threadIdx.x;
    if (fid >= F_TOTAL) return;
    const float* src; int nks; int rb;
    if (fid < F_WHH1)      { src = Whh0; nks = 4; rb = fid; }
    else if (fid < F_WIH1) { src = Whh1; nks = 4; rb = fid - F_WHH1; }
    else if (fid < F_WIH0) { src = Wih1; nks = 4; rb = fid - F_WIH1; }
    else                   { src = Wih0; nks = 2; rb = fid - F_WIH0; }
    int lane = rb & 63;
    int rem  = rb >> 6;
    int s    = rem % nks;
    int t    = (rem / nks) & 3;
    int w    = rem / (nks * 4);
    int row  = t * 128 + w * 16 + (lane & 15);
    int K    = nks * 32;
    int k0   = s * 32 + (lane >> 4) * 8;
    const float* p = src + (size_t)row * K + k0;
    unsigned short us[8];
    #pragma unroll
    for (int j = 0; j < 8; ++j)
        us[j] = __builtin_bit_cast(unsigned short, (_Float16)p[j]);
    int4 o;
    o.x = (int)((unsigned)us[0] | ((unsigned)us[1] << 16));
    o.y = (int)((unsigned)us[2] | ((unsigned)us[3] << 16));
    o.z = (int)((unsigned)us[4] | ((unsigned)us[5] << 16));
    o.w = (int)((unsigned)us[6] | ((unsigned)us[7] << 16));
    ws[fid] = o;
}

// ---------------- per-step body (R13 math; NO barrier inside) --------------
struct LaneCtx {
    int gsel, usel, u, xpr, base;
    bool writer, is_g, odd;
    int lk;
};

__device__ __forceinline__ void step_body(
    const LaneCtx& L, const int4 (&Ahi)[4][4],
    const float* xpt,
    const _Float16* hh_rd, const _Float16* hl_rd,
    _Float16* hh_wr, _Float16* hl_wr,
    float* h1f, float& c)
{
    const _Float16* bp = L.odd ? hl_rd : hh_rd;
    float xpv = xpt[L.xpr];
    f32x4 acc[4];
    #pragma unroll
    for (int t4 = 0; t4 < 4; ++t4) acc[t4] = (f32x4){0.f,0.f,0.f,0.f};
    #pragma unroll
    for (int s = 0; s < 4; ++s){
        f16x8 bv = ldb(&bp[s*32 + L.lk*8]);
        #pragma unroll
        for (int t4 = 0; t4 < 4; ++t4) acc[t4] = mfma16(Ahi[t4][s], bv, acc[t4]);
    }
    f32x4 ps;
    {
        f32x4 p01 = (L.gsel & 1) ? acc[1] : acc[0];
        f32x4 p23 = (L.gsel & 1) ? acc[3] : acc[2];
        ps = (L.gsel & 2) ? p23 : p01;
    }
    float own, oth;
    {
        float a01 = (L.usel & 1) ? ps[1] : ps[0];
        float a23 = (L.usel & 1) ? ps[3] : ps[2];
        own = (L.usel & 2) ? a23 : a01;
        float b01 = (L.usel & 1) ? ps[0] : ps[1];
        float b23 = (L.usel & 1) ? ps[2] : ps[3];
        oth = (L.usel & 2) ? b23 : b01;
    }
    float recv = __shfl_xor(oth, 1);
    float pre  = (L.odd ? (recv + SCL*own) : (own + SCL*recv)) + xpv;
    float z    = tanh_f(L.is_g ? pre : 0.5f*pre);
    float y    = L.is_g ? z : 0.5f*z + 0.5f;
    float gi = __shfl(y, L.base);
    float gf = __shfl(y, L.base | 4);
    float gg = __shfl(y, L.base | 8);
    float go = __shfl(y, L.base | 12);
    c = gf*c + gi*gg;
    float h = go * tanh_f(c);
    _Float16 hf = (_Float16)h;
    _Float16 hl = (_Float16)((h - (float)hf) * SCLI);
    if (L.writer){
        hh_wr[L.u] = hf;
        hl_wr[L.u] = hl;
        if (h1f) h1f[L.u] = h;
    }
}

// ---------------- fused dual-engine persistent kernel ----------------------
__global__
__attribute__((amdgpu_flat_work_group_size(1024,1024),
               amdgpu_waves_per_eu(4,4),
               amdgpu_num_vgpr(128)))
void lstm_fused(const float* __restrict__ x,
                const float* __restrict__ bih0, const float* __restrict__ bhh0,
                const float* __restrict__ bih1, const float* __restrict__ bhh1,
                const float* __restrict__ Wlin, const float* __restrict__ blin,
                const int4* __restrict__ ws,
                float* __restrict__ out)
{
    const int b    = blockIdx.x;
    const int tid  = threadIdx.x;
    const int lane = tid & 63;
    const int w    = tid >> 6;          // wave 0..15
    const int eng  = w >> 3;            // 0 = layer0, 1 = layer1
    const int we   = w & 7;             // engine-local wave 0..7
    const int lm   = lane & 15;
    const int lk   = lane >> 4;

    LaneCtx L;
    L.gsel = lm >> 2;  L.usel = lm & 3;  L.lk = lk;
    L.u    = we*16 + lk*4 + L.usel;
    L.xpr  = L.gsel*128 + we*16 + lk*4 + L.usel;
    L.base = lane & 0x33;
    L.writer = (L.gsel == 0);
    L.is_g   = (L.gsel == 2);
    L.odd    = (lane & 1);

    __shared__ __align__(16) float    xp0[TC][G4];        // 32,768
    __shared__ __align__(16) float    xp1[TC][G4];        // 32,768
    __shared__ __align__(16) _Float16 h0_hi[TC+1][136];   //  4,624
    __shared__ __align__(16) _Float16 h0_lo[TC+1][136];   //  4,624
    __shared__ __align__(16) _Float16 xc_hi[TC][72];      //  2,304
    __shared__ __align__(16) _Float16 xc_lo[TC][72];      //  2,304
    __shared__ __align__(16) _Float16 h1_hi[2][HH];       //    512
    __shared__ __align__(16) _Float16 h1_lo[2][HH];       //    512
    __shared__ __align__(16) float    h1f[HH];            //    512
    // total ~80.9 KB -> 1 block/CU (16 waves)

    if (tid < HH){ h0_hi[0][tid] = (_Float16)0.f; h0_lo[0][tid] = (_Float16)0.f; }
    else if (tid >= 512 && tid < 512 + HH){
        int u = tid - 512;
        h1_hi[0][u] = (_Float16)0.f; h1_lo[0][u] = (_Float16)0.f; h1f[u] = 0.f;
    }
    float c = 0.f;                       // per-engine cell state (lane-owned)
    const float* xb = x + (size_t)b * TSEQ * II;
    __syncthreads();

    #pragma unroll 1
    for (int ch = 0; ch <= NCH; ++ch){
        const bool l0 = (ch < NCH);
        const bool l1 = (ch > 0);

        // ---- Phase A: eng0 stages x chunk + carries h0 slot0 <- slot16 ----
        if (eng == 0 && l0){
            int i0 = tid, i1 = tid + 512;   // eng0 threads are tid 0..511
            float v0 = xb[(size_t)ch*TC*II + i0];
            float v1 = xb[(size_t)ch*TC*II + i1];
            _Float16 a0 = (_Float16)v0, a1 = (_Float16)v1;
            xc_hi[i0>>6][i0&63] = a0; xc_lo[i0>>6][i0&63] = (_Float16)((v0-(float)a0)*SCLI);
            xc_hi[i1>>6][i1&63] = a1; xc_lo[i1>>6][i1&63] = (_Float16)((v1-(float)a1)*SCLI);
            if (ch > 0 && tid < HH){
                h0_hi[0][tid] = h0_hi[TC][tid];
                h0_lo[0][tid] = h0_lo[TC][tid];
            }
        }
        __syncthreads();

        // ---- Phase B: proj xp0 (eng0) || proj xp1 from h0 hist (eng1) ----
        if (eng == 0 && l0){
            f32x4 acc[4], accL[4];
            #pragma unroll
            for (int t4 = 0; t4 < 4; ++t4){
                acc[t4]  = (f32x4){0.f,0.f,0.f,0.f};
                accL[t4] = (f32x4){0.f,0.f,0.f,0.f};
            }
            #pragma unroll
            for (int s = 0; s < 2; ++s){
                f16x8 bh = ldb(&xc_hi[lm][s*32 + lk*8]);
                f16x8 bl = ldb(&xc_lo[lm][s*32 + lk*8]);
                int4 ah[4];
                #pragma unroll
                for (int t4 = 0; t4 < 4; ++t4)
                    ah[t4] = ws[F_WIH0 + (((we*4 + t4)*2 + s) << 6) + lane];
                #pragma unroll
                for (int t4 = 0; t4 < 4; ++t4) acc[t4]  = mfma16(ah[t4], bh, acc[t4]);
                #pragma unroll
                for (int t4 = 0; t4 < 4; ++t4) accL[t4] = mfma16(ah[t4], bl, accL[t4]);
            }
            #pragma unroll
            for (int t4 = 0; t4 < 4; ++t4){
                int rowb = t4*128 + we*16 + lk*4;
                f32x4 bs = *(const f32x4*)(bih0+rowb) + *(const f32x4*)(bhh0+rowb);
                *(f32x4*)&xp0[lm][rowb] = acc[t4] + accL[t4]*SCL + bs;
            }
        } else if (eng == 1 && l1){
            f32x4 acc[4], accL[4];
            #pragma unroll
            for (int t4 = 0; t4 < 4; ++t4){
                acc[t4]  = (f32x4){0.f,0.f,0.f,0.f};
                accL[t4] = (f32x4){0.f,0.f,0.f,0.f};
            }
            #pragma unroll
            for (int s = 0; s < 4; ++s){
                f16x8 bh = ldb(&h0_hi[lm + 1][s*32 + lk*8]);
                f16x8 bl = ldb(&h0_lo[lm + 1][s*32 + lk*8]);
                int4 ah[4];
                #pragma unroll
                for (int t4 = 0; t4 < 4; ++t4)
                    ah[t4] = ws[F_WIH1 + (((we*4 + t4)*4 + s) << 6) + lane];
                #pragma unroll
                for (int t4 = 0; t4 < 4; ++t4) acc[t4]  = mfma16(ah[t4], bh, acc[t4]);
                #pragma unroll
                for (int t4 = 0; t4 < 4; ++t4) accL[t4] = mfma16(ah[t4], bl, accL[t4]);
            }
            #pragma unroll
            for (int t4 = 0; t4 < 4; ++t4){
                int rowb = t4*128 + we*16 + lk*4;
                f32x4 bs = *(const f32x4*)(bih1+rowb) + *(const f32x4*)(bhh1+rowb);
                *(f32x4*)&xp1[lm][rowb] = acc[t4] + accL[t4]*SCL + bs;
            }
        }
        __syncthreads();

        // ---- per-chunk weight regs (engine-specific Whh) ----
        int4 Ahi[4][4];
        {
            const int F = eng ? F_WHH1 : F_WHH0;
            #pragma unroll
            for (int t4 = 0; t4 < 4; ++t4)
                #pragma unroll
                for (int s = 0; s < 4; ++s)
                    Ahi[t4][s] = ws[F + (((we*4 + t4)*4 + s) << 6) + lane];
            #pragma unroll
            for (int t4 = 0; t4 < 4; ++t4)
                #pragma unroll
                for (int s = 0; s < 4; ++s) KEEP4I(Ahi[t4][s]);
        }

        // ---- serial pair loop: L0 step t (chunk ch) || L1 step t (ch-1) ----
        #pragma unroll 1
        for (int t = 0; t < TC; ++t){
            if (eng == 0){
                if (l0)
                    step_body(L, Ahi, &xp0[t][0],
                              &h0_hi[t][0], &h0_lo[t][0],
                              &h0_hi[t+1][0], &h0_lo[t+1][0],
                              nullptr, c);
            } else {
                if (l1)
                    step_body(L, Ahi, &xp1[t][0],
                              &h1_hi[t&1][0], &h1_lo[t&1][0],
                              &h1_hi[(t+1)&1][0], &h1_lo[(t+1)&1][0],
                              h1f, c);
            }
            __syncthreads();   // single shared barrier per PAIR-step
        }
    }

    // ---- final linear: out[b] = h1 . Wlin[0,:] + blin ----
    if (tid < 64){
        float s = h1f[tid]*Wlin[tid] + h1f[tid+64]*Wlin[tid+64];
        #pragma unroll
        for (int off = 32; off; off >>= 1) s += __shfl_down(s, off);
        if (tid == 0) out[b] = s + blin[0];
    }
}

extern "C" void kernel_launch(void* const* d_in, const int* in_sizes, int n_in,
                              void* d_out, int out_size, void* d_ws, size_t ws_size,
                              hipStream_t stream)
{
    const float* x    = (const float*)d_in[0];
    const float* Wih0 = (const float*)d_in[1];
    const float* Whh0 = (const float*)d_in[2];
    const float* bih0 = (const float*)d_in[3];
    const float* bhh0 = (const float*)d_in[4];
    const float* Wih1 = (const float*)d_in[5];
    const float* Whh1 = (const float*)d_in[6];
    const float* bih1 = (const float*)d_in[7];
    const float* bhh1 = (const float*)d_in[8];
    const float* Wlin = (const float*)d_in[9];
    const float* blin = (const float*)d_in[10];

    if (ws_size < (size_t)F_TOTAL * 16) return;

    int4* ws = (int4*)d_ws;
    hipLaunchKernelGGL(pack_w, dim3(F_TOTAL/256), dim3(256), 0, stream,
                       Wih0, Whh0, Wih1, Whh1, ws);
    hipLaunchKernelGGL(lstm_fused, dim3(NB), dim3(1024), 0, stream,
                       x, bih0, bhh0, bih1, bhh1, Wlin, blin,
                       ws, (float*)d_out);
}